// Round 5
// baseline (227.611 us; speedup 1.0000x reference)
//
#include <hip/hip_runtime.h>
#include <hip/hip_fp16.h>

// InteractionBlock, MI355X, round 5: slice-phased gather.
//
// y = out @ W3 + gathersum(out) @ (W2@W3) + (b2@W3 + b3)
// R4 post-mortem: EA (L2<->fabric) path saturates at ~3.25 TB/s; FETCH 152.8MB
// = ~19 compulsory + ~134 gather re-fetch. Floor: each of 8 XCDs must fetch
// the 12.8MB packed hot set once (~102MB). R5 removes the *capacity* misses:
// indices are pre-sorted per g into 13 address slices (idx>>12, ~1MB of rows
// each, padded to even counts with the zero row G); the fused kernel runs as
// a persistent 1024-block grid (exactly 4/CU, one generation) with a
// slice-major outer loop, so all blocks on an XCD stream the same <=2MB slice
// concurrently -> it stays L2-resident. Messages for a block's 48-49 g's
// accumulate in registers across slices. Epilogue = R4's MFMA (16x16x32 f16),
// B-frags straight from global (16KB, cache-resident) so LDS = X tile only.

constexpr int A  = 64;     // ao_vals
constexpr int K  = 32;     // neighbors
constexpr int NB = 1024;   // fused grid: exactly 4 blocks/CU on 256 CUs
constexpr int NSLICE = 13; // idx>>12, G+1 = 50001 -> slices 0..12
constexpr int SLOTS  = 48; // sorted slots per g (32 real + <=13 pads, even)
constexpr int XS = 136;    // X row stride in halves (16B-aligned rows, 4-bank shift)
constexpr int XROWS = 112; // 2 batches x 56 row slots (NR <= 49), 7 MFMA tiles
constexpr int MAXGW = 13;  // max g's per wave (ceil(49/4))

typedef _Float16 f16x8 __attribute__((ext_vector_type(8)));
typedef float    f32x4 __attribute__((ext_vector_type(4)));

// ---- kernel 1: WTg[n][k] = (half) concat(W2@W3, W3)[k][n]; bb = b2@W3+b3 ----
__global__ void wprep_kernel(const float* __restrict__ W2, const float* __restrict__ b2,
                             const float* __restrict__ W3, const float* __restrict__ b3,
                             __half* __restrict__ WTg, float* __restrict__ bb) {
  const int e = blockIdx.x * 256 + threadIdx.x;   // 0..4095
  const int n = e >> 6, k = e & 63;
  float acc = 0.f;
#pragma unroll
  for (int q = 0; q < A; ++q) acc = fmaf(W2[k * A + q], W3[q * A + n], acc);
  WTg[n * 128 + k]     = __float2half(acc);           // W23 (k rows 0..63)
  WTg[n * 128 + A + k] = __float2half(W3[k * A + n]); // W3  (k rows 64..127)
  if (blockIdx.x == 0 && threadIdx.x < A) {
    const int t = threadIdx.x;
    float b = b3[t];
#pragma unroll
    for (int q = 0; q < A; ++q) b = fmaf(b2[q], W3[q * A + t], b);
    bb[t] = b;
  }
}

// ---- kernel 2: pack out (fp32 [2][G][64]) -> packed ([G+1][64] half2) ----
// dword c of row g: c<32 -> batch0 element pair (2c,2c+1); else batch1.
// Row G is the materialized zero pad row (also the pad/dummy target).
__global__ void pack_kernel(const float2* __restrict__ out2,
                            __half2* __restrict__ packed, const int G) {
  const int d = blockIdx.x * 256 + threadIdx.x;
  if (d >= (G + 1) * 64) return;
  const int g = d >> 6, c = d & 63;
  float2 v = make_float2(0.f, 0.f);
  if (g < G) v = out2[(size_t)(c >> 5) * (G * 32) + (size_t)g * 32 + (c & 31)];
  packed[d] = __floats2half2_rn(v.x, v.y);
}

// ---- kernel 3: per-g counting sort of the 32 indices into 13 slices, each
// slice run padded to even length with index G (zero row -> exact no-op).
// Output: sorted[g][48] + offs[g] = 14 pair-offsets packed as bytes in int4.
__global__ void sort_kernel(const int* __restrict__ nbr, int* __restrict__ sorted,
                            int4* __restrict__ offs, const int G) {
  const int g = blockIdx.x * 256 + threadIdx.x;
  if (g >= G) return;
  int v[K];
#pragma unroll
  for (int k = 0; k < K; ++k) v[k] = nbr[g * K + k];
  int* dst = sorted + (size_t)g * SLOTS;
  unsigned b[NSLICE + 1];
  b[0] = 0;
  int pos = 0;
#pragma unroll
  for (int s = 0; s < NSLICE; ++s) {
    const int start = pos;
#pragma unroll
    for (int k = 0; k < K; ++k)
      if ((v[k] >> 12) == s) dst[pos++] = v[k];
    if ((pos - start) & 1) dst[pos++] = G;   // pad run to even with zero row
    b[s + 1] = (unsigned)(pos >> 1);         // pair offset
  }
  int4 o;
  o.x = (int)(b[0]  | (b[1]  << 8) | (b[2]  << 16) | (b[3]  << 24));
  o.y = (int)(b[4]  | (b[5]  << 8) | (b[6]  << 16) | (b[7]  << 24));
  o.z = (int)(b[8]  | (b[9]  << 8) | (b[10] << 16) | (b[11] << 24));
  o.w = (int)(b[12] | (b[13] << 8));
  offs[g] = o;
}

__device__ __forceinline__ int rl(int v, int l) {
  return __builtin_amdgcn_readlane(v, l);
}

// ---- kernel 4: persistent fused gather (slice-major) + MFMA epilogue ----
// LDS = X only (112 x 136 halves = 30.5 KB) -> >=4 blocks/CU at grid 1024.
__global__ __launch_bounds__(256, 4) void fused_kernel(
    const __half2* __restrict__ packed, const int* __restrict__ sorted,
    const int4* __restrict__ offs, const __half* __restrict__ WTg,
    const float* __restrict__ bb, float* __restrict__ y, const int G) {
  __shared__ __half X[XROWS * XS];   // rows: batch*56 + gl; cols: [m(64)|o(64)]

  const int tid = threadIdx.x;
  const int lane = tid & 63;
  const int w = tid >> 6;
  const int bid = blockIdx.x;
  const int g0 = (int)(((long long)bid * G) / NB);
  const int g1 = (int)(((long long)(bid + 1) * G) / NB);
  const int NR = g1 - g0;                       // 48 or 49
  const int w0 = g0 + (NR * w) / 4;
  const int w1 = g0 + (NR * (w + 1)) / 4;
  const int ng = w1 - w0;                       // 12 or 13 g's for this wave

  // Preload sorted index vectors (lane-held) and pair-offset quads (uniform).
  int idxv[MAXGW];
  int4 po4[MAXGW];
  __half2 acc[MAXGW];
  const __half2 z = __floats2half2_rn(0.f, 0.f);
  const int lslot = lane < SLOTS ? lane : SLOTS - 1;
#pragma unroll
  for (int gi = 0; gi < MAXGW; ++gi) {
    acc[gi] = z;
    if (gi < ng) {
      idxv[gi] = sorted[(size_t)(w0 + gi) * SLOTS + lslot];
      po4[gi] = offs[w0 + gi];
    } else {
      idxv[gi] = G;
      po4[gi] = make_int4(0, 0, 0, 0);
    }
  }

  // Slice-major gather: all co-resident blocks sweep slice s together, so the
  // per-XCD L2 working set is ~1-2 MB at any time (capacity misses -> 0).
#pragma unroll
  for (int s = 0; s < NSLICE; ++s) {
#pragma unroll
    for (int gi = 0; gi < MAXGW; ++gi) {
      if (gi < ng) {
        const unsigned pb[4] = {(unsigned)po4[gi].x, (unsigned)po4[gi].y,
                                (unsigned)po4[gi].z, (unsigned)po4[gi].w};
        const int p0 = (int)((pb[s >> 2] >> ((s & 3) * 8)) & 255u);
        const int p1 = (int)((pb[(s + 1) >> 2] >> (((s + 1) & 3) * 8)) & 255u);
        for (int p = p0; p < p1; ++p) {        // uniform pair loop
          const int i0 = rl(idxv[gi], 2 * p);  // dynamic-lane readlane -> SGPR
          const int i1 = rl(idxv[gi], 2 * p + 1);
          const __half2 u0 = packed[(size_t)i0 * 64 + lane];
          const __half2 u1 = packed[(size_t)i1 * 64 + lane];
          acc[gi] = __hadd2(acc[gi], u0);
          acc[gi] = __hadd2(acc[gi], u1);
        }
      }
    }
  }

  // Stage X: message (cols 0..63) + residual row (cols 64..127).
  const int e2 = 2 * (lane & 31);
  const int rb = (lane >> 5) * 56;
#pragma unroll
  for (int gi = 0; gi < MAXGW; ++gi) {
    if (gi < ng) {
      const int gl = (w0 - g0) + gi;
      const int row = rb + gl;
      *(__half2*)&X[row * XS + e2] = acc[gi];
      *(__half2*)&X[row * XS + A + e2] = packed[(size_t)(w0 + gi) * 64 + lane];
    }
  }
  __syncthreads();

  // MFMA epilogue: Y[112x64] = X[112x128] @ Wcat; 7 row-tiles over 4 waves.
  // A-frag A[m=lane&15][k=quad*8+j]; B-frag B[k=quad*8+j][n=lane&15] read
  // straight from WTg (n-major global, 16 KB, cache-resident).
  const int quad = lane >> 4, mn = lane & 15;
#pragma unroll
  for (int j = 0; j < 2; ++j) {
    const int t = w + 4 * j;
    if (t < 7) {
      f32x4 ac[4] = {{0.f, 0.f, 0.f, 0.f}, {0.f, 0.f, 0.f, 0.f},
                     {0.f, 0.f, 0.f, 0.f}, {0.f, 0.f, 0.f, 0.f}};
#pragma unroll
      for (int kt = 0; kt < 4; ++kt) {
        const int ko = kt * 32 + quad * 8;
        const f16x8 a = *(const f16x8*)&X[(t * 16 + mn) * XS + ko];
#pragma unroll
        for (int nt = 0; nt < 4; ++nt) {
          const f16x8 bfr = *(const f16x8*)&WTg[(nt * 16 + mn) * 128 + ko];
          ac[nt] = __builtin_amdgcn_mfma_f32_16x16x32_f16(a, bfr, ac[nt], 0, 0, 0);
        }
      }
#pragma unroll
      for (int nt = 0; nt < 4; ++nt) {
        const int col = nt * 16 + mn;
        const float bv = bb[col];
#pragma unroll
        for (int rg = 0; rg < 4; ++rg) {
          const int row = t * 16 + quad * 4 + rg;   // C/D: col=lane&15, row=quad*4+reg
          const int bt = row >= 56 ? 1 : 0;
          const int gl = row - 56 * bt;
          if (gl < NR)
            y[((size_t)bt * G + (g0 + gl)) * 64 + col] = ac[nt][rg] + bv;
        }
      }
    }
  }
}

extern "C" void kernel_launch(void* const* d_in, const int* in_sizes, int n_in,
                              void* d_out, int out_size, void* d_ws, size_t ws_size,
                              hipStream_t stream) {
  const float* out = (const float*)d_in[0];
  const int*   nbr = (const int*)d_in[1];
  const float* W2  = (const float*)d_in[2];
  const float* b2  = (const float*)d_in[3];
  const float* W3  = (const float*)d_in[4];
  const float* b3  = (const float*)d_in[5];
  float* y = (float*)d_out;
  const int G = in_sizes[1] / K;

  // ws: packed rows | offs (int4/g) | sorted (48 int/g) | WTg | bb  (~23.2 MB)
  __half2* packed = (__half2*)d_ws;
  const size_t pbytes = (size_t)(G + 1) * 64 * sizeof(__half2);
  int4* offs = (int4*)((char*)d_ws + pbytes);
  int* sorted = (int*)((char*)d_ws + pbytes + (size_t)G * sizeof(int4));
  __half* WTg = (__half*)((char*)d_ws + pbytes + (size_t)G * sizeof(int4) +
                          (size_t)G * SLOTS * sizeof(int));
  float* bbp = (float*)(WTg + 128 * 64);

  wprep_kernel<<<16, 256, 0, stream>>>(W2, b2, W3, b3, WTg, bbp);

  const int packTotal = (G + 1) * 64;
  pack_kernel<<<(packTotal + 255) / 256, 256, 0, stream>>>(
      (const float2*)out, packed, G);

  sort_kernel<<<(G + 255) / 256, 256, 0, stream>>>(nbr, sorted, offs, G);

  fused_kernel<<<NB, 256, 0, stream>>>(packed, sorted, offs, WTg, bbp, y, G);
}